// Round 8
// baseline (160.897 us; speedup 1.0000x reference)
//
#include <hip/hip_runtime.h>
#include <hip/hip_bf16.h>
#include <stdint.h>

#define B_DIM 4096
#define T_DIM 8
#define IN_DIM 1024
#define OUT_DIM 1024
#define R_DIM 32

#define BM 256
#define BN 256
#define BK 64
#define NKT (IN_DIM / BK)   // 16

typedef __bf16 bf16x8 __attribute__((ext_vector_type(8)));
typedef float  f32x4  __attribute__((ext_vector_type(4)));

#define VMCNT(n) asm volatile("s_waitcnt vmcnt(" #n ")" ::: "memory")
#define CFENCE() asm volatile("" ::: "memory")
#define BARRIER() do { CFENCE(); __builtin_amdgcn_s_barrier(); CFENCE(); } while (0)

// ---- helpers --------------------------------------------------------------

// round-to-nearest fp32->bf16, two packed into one u32 (lo in low half)
__device__ __forceinline__ uint32_t pack2_bf16(float a, float b) {
  uint32_t ua = __float_as_uint(a), ub = __float_as_uint(b);
  ua = (ua + 0x7FFFu + ((ua >> 16) & 1u)) >> 16;
  ub = (ub + 0x7FFFu + ((ub >> 16) & 1u)) & 0xFFFF0000u;
  return ua | ub;
}

// async global->LDS, 16B per lane; LDS dest is wave-uniform base + lane*16
__device__ __forceinline__ void gload_lds16(const void* g, void* l) {
  __builtin_amdgcn_global_load_lds(
      (const __attribute__((address_space(1))) void*)(uintptr_t)g,
      (__attribute__((address_space(3))) void*)(uint32_t)(uintptr_t)l,
      16, 0, 0);
}

// stage one 16KB half-tile (128 of 256 rows, 16-row-interleaved) of a K-tile
// into a 32KB LDS operand region. Linear dest + pre-swizzled source (rule 21).
__device__ __forceinline__ void stage_half(const uint16_t* gtile, int ktn,
                                           int half, uint8_t* ldsop,
                                           int wave, int lane) {
#pragma unroll
  for (int j = 0; j < 2; ++j) {
    int s = j * 64 + wave * 8 + (lane >> 3);      // slot 0..127 within half
    int c = lane & 7;                             // LDS 16B chunk within row
    int row = (s >> 4) * 32 + half * 16 + (s & 15);
    gload_lds16((const uint8_t*)(gtile + (size_t)row * IN_DIM + ktn * BK) +
                    ((c ^ (s & 7)) << 4),
                ldsop + half * 16384 + j * 8192 + wave * 1024);
  }
}

// fragment reads: slot = (row>>5)*16 + (row&15); chunk = (ks*4+kg) ^ (row&7)
__device__ __forceinline__ bf16x8 lds_frag(const uint8_t* op, int grp,
                                           int par, int ks,
                                           int l15, int kg, int l7) {
  return *(const bf16x8*)(op + par * 16384 + (grp >> 1) * 2048 + l15 * 128 +
                          ((((ks << 2) + kg) ^ l7) << 4));
}

// cvt helper: 32 fp32 -> 32 bf16 (8 float4 in, 4 uint4 out)
__device__ __forceinline__ void cvt32(const float* src, uint16_t* dst) {
  float4 v[8];
#pragma unroll
  for (int i = 0; i < 8; ++i) v[i] = *(const float4*)(src + i * 4);
#pragma unroll
  for (int i = 0; i < 4; ++i) {
    uint4 o;
    o.x = pack2_bf16(v[2 * i].x, v[2 * i].y);
    o.y = pack2_bf16(v[2 * i].z, v[2 * i].w);
    o.z = pack2_bf16(v[2 * i + 1].x, v[2 * i + 1].y);
    o.w = pack2_bf16(v[2 * i + 1].z, v[2 * i + 1].w);
    *(uint4*)(dst + i * 8) = o;
  }
}

// ---- L1: stage1 (blocks 0..1023) + x-cvt tasks 0-3 (blocks 1024..3071) ----
__global__ __launch_bounds__(256) void pre1(const float* __restrict__ first,
                                            const float* __restrict__ middle,
                                            float* __restrict__ a1,
                                            const float* __restrict__ x,
                                            uint16_t* __restrict__ xb) {
  int bid = blockIdx.x, tid = threadIdx.x;
  if (bid < 1024) {
    // A1[t][i][k] = sum_j first[t][j] * middle[j][i][k]
    int idx = bid * 256 + tid;                 // t*32768 + i*32 + k
    int t  = idx >> 15;
    int ik = idx & 32767;
    float acc = 0.f;
#pragma unroll
    for (int j = 0; j < R_DIM; ++j)
      acc = fmaf(first[t * R_DIM + j], middle[j * (IN_DIM * R_DIM) + ik], acc);
    a1[idx] = acc;
  } else {
    // cvt x[b][t][:] (t=0..3) -> xb[t][b][:] ; 8 rows per block
    int cb = bid - 1024;                       // 0..2047
    int row_in = tid >> 5;                     // 0..7
    int c0 = (tid & 31) * 32;                  // 32 floats per thread
    int R = cb * 8 + row_in;                   // 0..16383
    int b = R >> 2, t = R & 3;
    cvt32(x + ((size_t)b * T_DIM + t) * IN_DIM + c0,
          xb + ((size_t)t * B_DIM + b) * IN_DIM + c0);
  }
}

// ---- L2: stage2 (blocks 0..2047) + x-cvt tasks 4-5 (blocks 2048..3071) ----
__global__ __launch_bounds__(256) void pre2(const float* __restrict__ a1,
                                            const float* __restrict__ task,
                                            __hip_bfloat16* __restrict__ wT,
                                            const float* __restrict__ x,
                                            uint16_t* __restrict__ xb) {
  int bid = blockIdx.x;
  int tid = threadIdx.x;
  if (bid < 2048) {
    // w_T[t][o][i] = sum_k A1[t][i][k]*task[k][o]
    int t  = bid >> 8;
    int ob = (bid >> 4) & 15;
    int ib = bid & 15;
    __shared__ float A1s[64][33];
    __shared__ float Ts[32][64];
#pragma unroll
    for (int r = 0; r < 8; ++r) {
      int idx2 = tid + 256 * r;
      int il = idx2 >> 5, k = idx2 & 31;
      A1s[il][k] = a1[t * (IN_DIM * R_DIM) + (ib * 64 + il) * R_DIM + k];
    }
#pragma unroll
    for (int r = 0; r < 8; ++r) {
      int idx2 = tid + 256 * r;
      int k = idx2 >> 6, ol = idx2 & 63;
      Ts[k][ol] = task[k * OUT_DIM + ob * 64 + ol];
    }
    __syncthreads();
    int il = tid & 63;
    int og = tid >> 6;
    float acc[16];
#pragma unroll
    for (int r = 0; r < 16; ++r) acc[r] = 0.f;
#pragma unroll
    for (int k = 0; k < 32; ++k) {
      float a = A1s[il][k];
#pragma unroll
      for (int r = 0; r < 16; ++r)
        acc[r] = fmaf(a, Ts[k][og * 16 + r], acc[r]);
    }
#pragma unroll
    for (int r = 0; r < 16; ++r) {
      size_t o = (size_t)ob * 64 + og * 16 + r;
      wT[((size_t)t * OUT_DIM + o) * IN_DIM + ib * 64 + il] = __float2bfloat16(acc[r]);
    }
  } else {
    // cvt tasks 4-5 ; 8 rows per block
    int cb = bid - 2048;                       // 0..1023
    int row_in = tid >> 5;
    int c0 = (tid & 31) * 32;
    int R = cb * 8 + row_in;                   // 0..8191
    int b = R >> 1, t = 4 + (R & 1);
    cvt32(x + ((size_t)b * T_DIM + t) * IN_DIM + c0,
          xb + ((size_t)t * B_DIM + b) * IN_DIM + c0);
  }
}

// ---- GEMM: R4-verbatim 256x256xBK64 8-phase counted-vmcnt bf16 GEMM -------
// grid 256 (one 4-task group), t = t_base + (bid&3) -> each XCD serves one
// task (B panel 2MB L2-resident). Optional epilogue cvt of tasks 6-7 (L3).
__global__ __launch_bounds__(512, 2) void tt_gemm(const uint16_t* __restrict__ XB,
                                                  const uint16_t* __restrict__ WT,
                                                  float* __restrict__ O,
                                                  const float* __restrict__ Xf,
                                                  uint16_t* __restrict__ XBw,
                                                  int t_base, int doCvt) {
  extern __shared__ uint8_t sm[];
  int bid = blockIdx.x;
  const int t  = t_base + (bid & 3);
  const int l  = bid >> 2;                // 0..63 within group
  const int mt = l >> 2;                  // 0..15
  const int nt = l & 3;                   // n-fastest: x panel L2-shared

  const int tid  = threadIdx.x;
  const int lane = tid & 63;
  const int wave = tid >> 6;              // 0..7
  const int wr = wave >> 2, wc = wave & 3;
  const int wr8 = wr * 8, wc4 = wc * 4;
  const int l15 = lane & 15, l7 = lane & 7, kg = lane >> 4;

  const uint16_t* gA = XB + ((size_t)t * B_DIM + mt * BM) * IN_DIM;
  const uint16_t* gB = WT + ((size_t)t * OUT_DIM + nt * BN) * IN_DIM;

  f32x4 acc[8][4] = {};
  bf16x8 afr[4][2], bfr0[2][2], bfr1[2][2];

  // ---- prologue: K-tile 0 fully into buf0, drain once
  stage_half(gA, 0, 0, sm, wave, lane);
  stage_half(gB, 0, 0, sm + 32768, wave, lane);
  stage_half(gA, 0, 1, sm, wave, lane);
  stage_half(gB, 0, 1, sm + 32768, wave, lane);
  VMCNT(0);
  BARRIER();

#pragma unroll 2
  for (int kt = 0; kt < NKT; ++kt) {
    const int P = kt & 1;
    const uint8_t* bA = sm + P * 65536;
    const uint8_t* bB = bA + 32768;
    uint8_t* nA = sm + (P ^ 1) * 65536;
    uint8_t* nB = nA + 32768;
    const bool st = (kt + 1) < NKT;

    // ===== P1: (mp0, np0)
#pragma unroll
    for (int mo = 0; mo < 4; ++mo)
#pragma unroll
      for (int ks = 0; ks < 2; ++ks)
        afr[mo][ks] = lds_frag(bA, wr8 + mo * 2, 0, ks, l15, kg, l7);
#pragma unroll
    for (int no = 0; no < 2; ++no)
#pragma unroll
      for (int ks = 0; ks < 2; ++ks)
        bfr0[no][ks] = lds_frag(bB, wc4 + no * 2, 0, ks, l15, kg, l7);
    if (st) stage_half(gA, kt + 1, 0, nA, wave, lane);
    if (kt == NKT - 1) { VMCNT(0); } else { VMCNT(2); }   // cover Ah1,Bh1(kt)
    BARRIER();
    __builtin_amdgcn_s_setprio(1);
#pragma unroll
    for (int mo = 0; mo < 4; ++mo)
#pragma unroll
      for (int no = 0; no < 2; ++no)
#pragma unroll
        for (int ks = 0; ks < 2; ++ks)
          acc[mo * 2][no * 2] = __builtin_amdgcn_mfma_f32_16x16x32_bf16(
              afr[mo][ks], bfr0[no][ks], acc[mo * 2][no * 2], 0, 0, 0);
    __builtin_amdgcn_s_setprio(0);
    BARRIER();

    // ===== P2: (mp0, np1)
#pragma unroll
    for (int no = 0; no < 2; ++no)
#pragma unroll
      for (int ks = 0; ks < 2; ++ks)
        bfr1[no][ks] = lds_frag(bB, wc4 + no * 2 + 1, 1, ks, l15, kg, l7);
    if (st) stage_half(gB, kt + 1, 0, nB, wave, lane);
    BARRIER();
    __builtin_amdgcn_s_setprio(1);
#pragma unroll
    for (int mo = 0; mo < 4; ++mo)
#pragma unroll
      for (int no = 0; no < 2; ++no)
#pragma unroll
        for (int ks = 0; ks < 2; ++ks)
          acc[mo * 2][no * 2 + 1] = __builtin_amdgcn_mfma_f32_16x16x32_bf16(
              afr[mo][ks], bfr1[no][ks], acc[mo * 2][no * 2 + 1], 0, 0, 0);
    __builtin_amdgcn_s_setprio(0);
    BARRIER();

    // ===== P3: (mp1, np0)
#pragma unroll
    for (int mo = 0; mo < 4; ++mo)
#pragma unroll
      for (int ks = 0; ks < 2; ++ks)
        afr[mo][ks] = lds_frag(bA, wr8 + mo * 2 + 1, 1, ks, l15, kg, l7);
    if (st) stage_half(gA, kt + 1, 1, nA, wave, lane);
    BARRIER();
    __builtin_amdgcn_s_setprio(1);
#pragma unroll
    for (int mo = 0; mo < 4; ++mo)
#pragma unroll
      for (int no = 0; no < 2; ++no)
#pragma unroll
        for (int ks = 0; ks < 2; ++ks)
          acc[mo * 2 + 1][no * 2] = __builtin_amdgcn_mfma_f32_16x16x32_bf16(
              afr[mo][ks], bfr0[no][ks], acc[mo * 2 + 1][no * 2], 0, 0, 0);
    __builtin_amdgcn_s_setprio(0);
    BARRIER();

    // ===== P4: (mp1, np1)
    if (st) stage_half(gB, kt + 1, 1, nB, wave, lane);
    if (st) { VMCNT(4); }                  // cover Ah0,Bh0(kt+1); keep 4 flying
    BARRIER();
    __builtin_amdgcn_s_setprio(1);
#pragma unroll
    for (int mo = 0; mo < 4; ++mo)
#pragma unroll
      for (int no = 0; no < 2; ++no)
#pragma unroll
        for (int ks = 0; ks < 2; ++ks)
          acc[mo * 2 + 1][no * 2 + 1] = __builtin_amdgcn_mfma_f32_16x16x32_bf16(
              afr[mo][ks], bfr1[no][ks], acc[mo * 2 + 1][no * 2 + 1], 0, 0, 0);
    __builtin_amdgcn_s_setprio(0);
    BARRIER();
  }

  // ---- epilogue: C/D layout col=lane&15, row=(lane>>4)*4+j (m89-verified)
  const int crow0 = mt * BM + wr * 128 + (lane >> 4) * 4;
  const int ccol0 = nt * BN + wc * 64 + (lane & 15);
#pragma unroll
  for (int m = 0; m < 8; ++m) {
#pragma unroll
    for (int j = 0; j < 4; ++j) {
      size_t rowoff =
          ((size_t)(crow0 + m * 16 + j) * T_DIM + t) * OUT_DIM + ccol0;
#pragma unroll
      for (int n = 0; n < 4; ++n)
        O[rowoff + n * 16] = acc[m][n][j];
    }
  }

  // ---- embedded cvt of tasks 6-7 (L3 only): rides the store-drain window
  if (doCvt) {
    const int row_in = tid >> 4;           // 0..31 rows per block
    const int c0 = (tid & 15) * 64;        // 64 floats per thread
    const int R = bid * 32 + row_in;       // 0..8191 over (b, t6|t7)
    const int b = R >> 1, tt2 = 6 + (R & 1);
    const float* src = Xf + ((size_t)b * T_DIM + tt2) * IN_DIM + c0;
    uint16_t* dst = XBw + ((size_t)tt2 * B_DIM + b) * IN_DIM + c0;
    cvt32(src, dst);
    cvt32(src + 32, dst + 32);
  }
}

// ---- host ------------------------------------------------------------------
extern "C" void kernel_launch(void* const* d_in, const int* in_sizes, int n_in,
                              void* d_out, int out_size, void* d_ws, size_t ws_size,
                              hipStream_t stream) {
  const float* x      = (const float*)d_in[0];
  const float* first  = (const float*)d_in[1];
  const float* middle = (const float*)d_in[2];
  const float* task   = (const float*)d_in[3];
  float* out = (float*)d_out;

  // ws: a1 fp32 1MB @0; wT bf16 16MB @1MB; xb bf16 64MB @17MB
  float* a1 = (float*)d_ws;
  __hip_bfloat16* wT = (__hip_bfloat16*)((uint8_t*)d_ws + (1u << 20));
  uint16_t* xb = (uint16_t*)((uint8_t*)d_ws + (17u << 20));

  hipFuncSetAttribute((const void*)tt_gemm,
                      hipFuncAttributeMaxDynamicSharedMemorySize, 131072);

  // L1: stage1 + cvt(t0-3)   (3072 blocks)
  pre1<<<3072, 256, 0, stream>>>(first, middle, a1, x, xb);
  // L2: stage2 + cvt(t4-5)   (3072 blocks)
  pre2<<<3072, 256, 0, stream>>>(a1, task, wT, x, xb);
  // L3: gemm t0-3 + embedded cvt(t6-7)
  tt_gemm<<<256, 512, 131072, stream>>>(xb, (const uint16_t*)wT, out,
                                        x, xb, 0, 1);
  // L4: gemm t4-7
  tt_gemm<<<256, 512, 131072, stream>>>(xb, (const uint16_t*)wT, out,
                                        x, xb, 4, 0);
}